// Round 3
// baseline (413.386 us; speedup 1.0000x reference)
//
#include <hip/hip_runtime.h>

#define D 128
#define NH 8
#define CH 16
#define NEG 0.2f
#define BN_EPS 1e-5f
#define MAXDEG 32
#define NSLICE 32
#define WROWS 144            // 128 weight cols + 16 score cols

typedef unsigned int uint;
typedef unsigned short ushort;
typedef __attribute__((ext_vector_type(8))) short bfrag;
typedef __attribute__((ext_vector_type(4))) float ffrag;

__device__ __forceinline__ float bf_lo(uint u){ return __uint_as_float(u << 16); }
__device__ __forceinline__ float bf_hi(uint u){ return __uint_as_float(u & 0xffff0000u); }
__device__ __forceinline__ float bf2f(ushort s){ return __uint_as_float(((uint)s) << 16); }
__device__ __forceinline__ ushort f2b(float f){
  uint u = __float_as_uint(f);
  u += 0x7fffu + ((u >> 16) & 1u);      // round-to-nearest-even
  return (ushort)(u >> 16);
}

// ---------------- fused setup: init | gbound | wprep | wsc | scatter ----------------
__global__ void k_setup(const float* __restrict__ x, const float* __restrict__ Wp,
                        const float* __restrict__ bp, ushort* __restrict__ h,
                        const int* __restrict__ batch, int* __restrict__ gs,
                        const float* __restrict__ Wg, const float* __restrict__ asrc,
                        const float* __restrict__ adst, ushort* __restrict__ WtB,
                        const int* __restrict__ ei, int* __restrict__ deg,
                        int* __restrict__ col,
                        int n, int G, int WTOT, int E,
                        int bInit, int bGb, int bWp, int bWsc){
  int bid = blockIdx.x;
  int t = threadIdx.x;
  if (bid < bInit){
    int i = bid*256 + t;
    if (i >= n*32) return;
    int nid = i >> 5, d4 = (i & 31)*4;
    const float* xr = x + nid*16;
    float s[4] = { bp[d4], bp[d4+1], bp[d4+2], bp[d4+3] };
#pragma unroll
    for (int k = 0; k < 16; k++){
      float xv = xr[k];
      const float* wr = Wp + k*D + d4;
      s[0] += xv*wr[0]; s[1] += xv*wr[1]; s[2] += xv*wr[2]; s[3] += xv*wr[3];
    }
    uint2 o;
    o.x = ((uint)f2b(fmaxf(s[0],0.f))) | (((uint)f2b(fmaxf(s[1],0.f))) << 16);
    o.y = ((uint)f2b(fmaxf(s[2],0.f))) | (((uint)f2b(fmaxf(s[3],0.f))) << 16);
    *(uint2*)(h + (size_t)nid*D + d4) = o;
  } else if (bid < bInit + bGb){
    int i = (bid - bInit)*256 + t;
    if (i >= n) return;
    int b = batch[i];
    int bpv = (i == 0) ? -1 : batch[i-1];
    for (int g = bpv + 1; g <= b; g++) gs[g] = i;
    if (i == n-1) for (int g = b + 1; g <= G; g++) gs[g] = n;
  } else if (bid < bInit + bGb + bWp){
    int i = (bid - bInit - bGb)*256 + t;
    if (i >= WTOT) return;
    int l = i >> 14, r = i & 16383, nn = r >> 7, kk = r & 127;
    WtB[(size_t)l*WROWS*D + nn*D + kk] = f2b(Wg[(size_t)l*16384 + kk*128 + nn]);
  } else if (bid < bInit + bGb + bWp + bWsc){
    int i = (bid - bInit - bGb - bWp)*256 + t;
    int wscTot = (WTOT >> 14)*16*128;     // L*16*128
    if (i >= wscTot) return;
    int l = i >> 11, r = i & 2047, j = r >> 7, k = r & 127;
    const float* wrow = Wg + (size_t)l*16384 + k*128;
    float s = 0.f;
    if (j < 8){
      const float* av = asrc + l*128 + j*16;
#pragma unroll
      for (int c = 0; c < 16; c++) s += wrow[j*16 + c] * av[c];
    } else {
      const float* av = adst + l*128 + (j - 8)*16;
#pragma unroll
      for (int c = 0; c < 16; c++) s += wrow[(j - 8)*16 + c] * av[c];
    }
    WtB[(size_t)l*WROWS*D + (128 + j)*D + k] = f2b(s);
  } else {
    int e = (bid - bInit - bGb - bWp - bWsc)*256 + t;
    if (e < E){
      int d = ei[E + e];
      int pos = atomicAdd(&deg[d], 1);
      if (pos < MAXDEG) col[(size_t)d*MAXDEG + pos] = ei[e];
    }
  }
}

// ---------------- MFMA bf16 GEMM 256x144: B staged in LDS once per block ----------------
__global__ __launch_bounds__(512) void k_gemm(const ushort* __restrict__ hin,
                                              const ushort* __restrict__ WtB,
                                              ushort* __restrict__ xh,
                                              float* __restrict__ sc2,
                                              const float* __restrict__ bnsum,
                                              const float* __restrict__ gamma,
                                              const float* __restrict__ beta,
                                              int n, int first){
  __shared__ __align__(16) ushort wL[WROWS*136];   // 144 rows x (128+8 pad) = 39168 B
  __shared__ float sS[128], sB[128];
  int t = threadIdx.x;
  int wid = t >> 6, lane = t & 63, l15 = lane & 15, quad = lane >> 4;
  int n0 = blockIdx.x * 256;
  int rbase = wid*32;                  // wave-private row base (0..224)

  if (t < 128){
    float sc, sh;
    if (first){ sc = 1.f; sh = 0.f; }
    else {
      float s = 0.f, s2 = 0.f;
#pragma unroll 8
      for (int sl = 0; sl < NSLICE; sl++){
        s  += bnsum[sl*256 + t];
        s2 += bnsum[sl*256 + 128 + t];
      }
      float invn = 1.0f / (float)n;
      float mu = s * invn;
      float var = s2 * invn - mu*mu;
      sc = gamma[t] * rsqrtf(var + BN_EPS);
      sh = beta[t] - mu*sc;
    }
    sS[t] = sc; sB[t] = sh;
  }
  // stage B: 144 rows x 16 uint4 = 2304 uint4 over 512 threads
#pragma unroll
  for (int i = 0; i < 5; i++){
    int u = t + i*512;
    if (u < WROWS*16){
      int r = u >> 4, c8 = u & 15;
      *(uint4*)(wL + r*136 + c8*8) = *(const uint4*)(WtB + (size_t)r*D + c8*8);
    }
  }
  __syncthreads();   // the only barrier

  // A fragments: direct global load (16B, aligned), BN+ReLU in registers
  bfrag a[2][4];
#pragma unroll
  for (int mt = 0; mt < 2; mt++){
    int row = n0 + rbase + mt*16 + l15;
#pragma unroll
    for (int ks = 0; ks < 4; ks++){
      union { bfrag b; ushort us[8]; } in, ov;
      in.b = (bfrag){0,0,0,0,0,0,0,0};
      if (row < n) in.b = *(const bfrag*)(hin + (size_t)row*D + ks*32 + quad*8);
      int kb = ks*32 + quad*8;
#pragma unroll
      for (int j = 0; j < 8; j++){
        float f = bf2f(in.us[j])*sS[kb + j] + sB[kb + j];
        ov.us[j] = f2b(f > 0.f ? f : 0.f);
      }
      a[mt][ks] = ov.b;
    }
  }

  ffrag acc[2][9];
#pragma unroll
  for (int mt = 0; mt < 2; mt++)
#pragma unroll
    for (int nt = 0; nt < 9; nt++) acc[mt][nt] = (ffrag){0.f,0.f,0.f,0.f};

  // MFMA with LDS-resident B; nt==8 is the score-column tile
#pragma unroll
  for (int nt = 0; nt < 9; nt++){
#pragma unroll
    for (int ks = 0; ks < 4; ks++){
      bfrag b = *(const bfrag*)(wL + (nt*16 + l15)*136 + ks*32 + quad*8);
      acc[0][nt] = __builtin_amdgcn_mfma_f32_16x16x32_bf16(a[0][ks], b, acc[0][nt], 0, 0, 0);
      acc[1][nt] = __builtin_amdgcn_mfma_f32_16x16x32_bf16(a[1][ks], b, acc[1][nt], 0, 0, 0);
    }
  }

  // epilogue: direct stores, no LDS. C mapping: row = rbase+mt*16+quad*4+r, col = nt*16+l15.
#pragma unroll
  for (int mt = 0; mt < 2; mt++)
#pragma unroll
    for (int r = 0; r < 4; r++){
      int grow = n0 + rbase + mt*16 + quad*4 + r;
      if (grow < n){
        sc2[(size_t)grow*16 + l15] = acc[mt][8][r];
        ushort* xr = xh + (size_t)grow*D + l15;
#pragma unroll
        for (int nt = 0; nt < 8; nt++)
          xr[nt*16] = f2b(acc[mt][nt][r]);
      }
    }
}

// ---------------- aggregation: 2 nodes/wave, IN-LANE softmax (no cross-lane ops) -------
// Each lane owns channels (2l, 2l+1), both in head l>>3. The lane loads the 8 neighbor
// source-scores for its head (same addr within each 8-lane head group -> broadcast),
// computes the full softmax in-register (max-tree + exp + sum), and applies weights
// directly. No shuffles anywhere: the dependency chain is purely in-lane and the two
// nodes' chains interleave freely.
__global__ __launch_bounds__(512) void k_agg(const uint* __restrict__ xh32,
                                             const float* __restrict__ sc2,
                                             const int* __restrict__ deg,
                                             const int* __restrict__ col,
                                             const float* __restrict__ bg,
                                             ushort* __restrict__ hout,
                                             float* __restrict__ bnsum, int n){
  int wv = threadIdx.x >> 6;
  int l  = threadIdx.x & 63;
  int hd = l >> 3;                 // head for this lane's channel pair
  int n0 = (blockIdx.x*8 + wv)*2;
  int n1 = n0 + 1;
  bool vA = n0 < n, vB = n1 < n;
  int na = vA ? n0 : 0, nb = vB ? n1 : 0;

  float bnS0=0.f, bnS1=0.f, bnQ0=0.f, bnQ1=0.f;
  float b0 = bg[2*l], b1 = bg[2*l + 1];

  // ---- prefetch: chunk 1 of both nodes ----
  int cntA = deg[na]; if (cntA > MAXDEG) cntA = MAXDEG; if (!vA) cntA = 0;
  int cntB = deg[nb]; if (cntB > MAXDEG) cntB = MAXDEG; if (!vB) cntB = 0;
  const int* cbA = col + na*MAXDEG;
  const int* cbB = col + nb*MAXDEG;
  int idxA[8], idxB[8];
#pragma unroll
  for (int j = 0; j < 8; j++){
    int ia = cbA[j]; idxA[j] = (j < cntA) ? ia : na;   // col NOT pre-zeroed: select first
    int ib = cbB[j]; idxB[j] = (j < cntB) ? ib : nb;
  }
  float adA = sc2[na*16 + 8 + hd], adB = sc2[nb*16 + 8 + hd];
  float asA = sc2[na*16 + hd],     asB = sc2[nb*16 + hd];
  uint selfA = xh32[na*64 + l],    selfB = xh32[nb*64 + l];
  float sA[8], sB_[8];
#pragma unroll
  for (int j = 0; j < 8; j++){ sA[j] = sc2[idxA[j]*16 + hd]; sB_[j] = sc2[idxB[j]*16 + hd]; }
  uint gA[8], gB[8];
#pragma unroll
  for (int j = 0; j < 8; j++){ gA[j] = xh32[idxA[j]*64 + l]; gB[j] = xh32[idxB[j]*64 + l]; }

  // ---- in-lane scores ----
  float eA[8], eB[8];
#pragma unroll
  for (int j = 0; j < 8; j++){
    float ea = sA[j]  + adA; ea = ea > 0.f ? ea : NEG*ea;
    float eb = sB_[j] + adB; eb = eb > 0.f ? eb : NEG*eb;
    eA[j] = (j < cntA) ? ea : -1e30f;
    eB[j] = (j < cntB) ? eb : -1e30f;
  }
  float e0A = asA + adA; e0A = e0A > 0.f ? e0A : NEG*e0A;
  float e0B = asB + adB; e0B = e0B > 0.f ? e0B : NEG*e0B;
  // max tree (depth 4 incl. self)
  float mA = fmaxf(fmaxf(fmaxf(eA[0],eA[1]), fmaxf(eA[2],eA[3])),
                   fmaxf(fmaxf(eA[4],eA[5]), fmaxf(eA[6],eA[7])));
  float mB = fmaxf(fmaxf(fmaxf(eB[0],eB[1]), fmaxf(eB[2],eB[3])),
                   fmaxf(fmaxf(eB[4],eB[5]), fmaxf(eB[6],eB[7])));
  mA = fmaxf(mA, e0A);
  mB = fmaxf(mB, e0B);
  float w0A = __expf(e0A - mA), w0B = __expf(e0B - mB);
  float denA = w0A, denB = w0B;
  float accA0 = w0A*bf_lo(selfA), accA1 = w0A*bf_hi(selfA);
  float accB0 = w0B*bf_lo(selfB), accB1 = w0B*bf_hi(selfB);
#pragma unroll
  for (int j = 0; j < 8; j++){
    float wa = __expf(eA[j] - mA);        // exp(-1e30 - m) == 0 -> masks invalid slots
    float wb = __expf(eB[j] - mB);
    denA += wa; denB += wb;
    accA0 += wa*bf_lo(gA[j]); accA1 += wa*bf_hi(gA[j]);
    accB0 += wb*bf_lo(gB[j]); accB1 += wb*bf_hi(gB[j]);
  }

  // ---- rare remainders (deg > 8), online rescale, still in-lane ----
  for (int c0 = 8; c0 < cntA; c0 += 8){
    int idx2[8];
#pragma unroll
    for (int j = 0; j < 8; j++){ int v = cbA[c0 + j]; idx2[j] = (c0 + j < cntA) ? v : na; }
    float s2v[8]; uint g2[8];
#pragma unroll
    for (int j = 0; j < 8; j++) s2v[j] = sc2[idx2[j]*16 + hd];
#pragma unroll
    for (int j = 0; j < 8; j++) g2[j] = xh32[idx2[j]*64 + l];
    float e2[8];
#pragma unroll
    for (int j = 0; j < 8; j++){
      float ee = s2v[j] + adA; ee = ee > 0.f ? ee : NEG*ee;
      e2[j] = (c0 + j < cntA) ? ee : -1e30f;
    }
    float m2 = fmaxf(fmaxf(fmaxf(e2[0],e2[1]), fmaxf(e2[2],e2[3])),
                     fmaxf(fmaxf(e2[4],e2[5]), fmaxf(e2[6],e2[7])));
    float mn = fmaxf(mA, m2);
    float r = __expf(mA - mn);
    denA *= r; accA0 *= r; accA1 *= r;
#pragma unroll
    for (int j = 0; j < 8; j++){
      float w = __expf(e2[j] - mn);
      denA += w; accA0 += w*bf_lo(g2[j]); accA1 += w*bf_hi(g2[j]);
    }
    mA = mn;
  }
  for (int c0 = 8; c0 < cntB; c0 += 8){
    int idx2[8];
#pragma unroll
    for (int j = 0; j < 8; j++){ int v = cbB[c0 + j]; idx2[j] = (c0 + j < cntB) ? v : nb; }
    float s2v[8]; uint g2[8];
#pragma unroll
    for (int j = 0; j < 8; j++) s2v[j] = sc2[idx2[j]*16 + hd];
#pragma unroll
    for (int j = 0; j < 8; j++) g2[j] = xh32[idx2[j]*64 + l];
    float e2[8];
#pragma unroll
    for (int j = 0; j < 8; j++){
      float ee = s2v[j] + adB; ee = ee > 0.f ? ee : NEG*ee;
      e2[j] = (c0 + j < cntB) ? ee : -1e30f;
    }
    float m2 = fmaxf(fmaxf(fmaxf(e2[0],e2[1]), fmaxf(e2[2],e2[3])),
                     fmaxf(fmaxf(e2[4],e2[5]), fmaxf(e2[6],e2[7])));
    float mn = fmaxf(mB, m2);
    float r = __expf(mB - mn);
    denB *= r; accB0 *= r; accB1 *= r;
#pragma unroll
    for (int j = 0; j < 8; j++){
      float w = __expf(e2[j] - mn);
      denB += w; accB0 += w*bf_lo(g2[j]); accB1 += w*bf_hi(g2[j]);
    }
    mB = mn;
  }

  // ---- finalize ----
  float invA = 1.0f / denA, invB = 1.0f / denB;
  float oA0 = accA0*invA + b0, oA1 = accA1*invA + b1;
  float oB0 = accB0*invB + b0, oB1 = accB1*invB + b1;
  if (vA){
    uint p = ((uint)f2b(oA0)) | (((uint)f2b(oA1)) << 16);
    ((uint*)hout)[n0*64 + l] = p;
    bnS0 += oA0; bnS1 += oA1; bnQ0 += oA0*oA0; bnQ1 += oA1*oA1;
  }
  if (vB){
    uint p = ((uint)f2b(oB0)) | (((uint)f2b(oB1)) << 16);
    ((uint*)hout)[n1*64 + l] = p;
    bnS0 += oB0; bnS1 += oB1; bnQ0 += oB0*oB0; bnQ1 += oB1*oB1;
  }

  // ---- block BN reduction ----
  __shared__ float red[8][64][4];
  red[wv][l][0] = bnS0; red[wv][l][1] = bnS1; red[wv][l][2] = bnQ0; red[wv][l][3] = bnQ1;
  __syncthreads();
  if (wv == 0){
    float t0 = 0.f, t1 = 0.f, t2 = 0.f, t3 = 0.f;
#pragma unroll
    for (int k = 0; k < 8; k++){
      t0 += red[k][l][0]; t1 += red[k][l][1];
      t2 += red[k][l][2]; t3 += red[k][l][3];
    }
    float* bs = bnsum + (blockIdx.x & (NSLICE - 1))*256;
    atomicAdd(&bs[2*l],       t0);
    atomicAdd(&bs[2*l + 1],   t1);
    atomicAdd(&bs[128 + 2*l], t2);
    atomicAdd(&bs[129 + 2*l], t3);
  }
}

// ---------------- fused pool (BN+ReLU) + output heads ----------------
__global__ __launch_bounds__(128) void k_poolheads(const ushort* __restrict__ h,
                                                   const int* __restrict__ gs,
                                                   const float* __restrict__ bnsum,
                                                   const float* __restrict__ gamma,
                                                   const float* __restrict__ beta,
                                                   const float* __restrict__ hW1,
                                                   const float* __restrict__ hb1,
                                                   const float* __restrict__ hW2,
                                                   const float* __restrict__ hb2,
                                                   float* __restrict__ out, int n){
  int g = blockIdx.x;
  int t = threadIdx.x;
  __shared__ float sp[128];
  int st = gs[g], en = gs[g + 1];
  float sm = 0.f, s2 = 0.f;
#pragma unroll 8
  for (int sl = 0; sl < NSLICE; sl++){
    sm += bnsum[sl*256 + t];
    s2 += bnsum[sl*256 + 128 + t];
  }
  float invn = 1.0f / (float)n;
  float mu = sm * invn;
  float var = s2 * invn - mu*mu;
  float sc = gamma[t] * rsqrtf(var + BN_EPS);
  float sh = beta[t] - mu*sc;
  float s = 0.f;
  for (int r = st; r < en; r++){
    float v = bf2f(h[(size_t)r*D + t]) * sc + sh;
    s += v > 0.f ? v : 0.f;
  }
  float cnt = (float)(en - st);
  sp[t] = s / fmaxf(cnt, 1.0f);
  __syncthreads();
  int wv = t >> 6, m = t & 63;
  for (int k = wv; k < 3; k += 2){
    float acc = hb1[k*64 + m];
    const float* w = hW1 + k*8192 + m;      // [d][m], coalesced over m
#pragma unroll 16
    for (int d = 0; d < 128; d++) acc += sp[d] * w[d*64];
    float val = fmaxf(acc, 0.f) * hW2[k*64 + m];
#pragma unroll
    for (int off = 32; off; off >>= 1) val += __shfl_down(val, off);
    if (m == 0) out[(size_t)g*3 + k] = val + hb2[k];
  }
}

// ---------------- launch ----------------
extern "C" void kernel_launch(void* const* d_in, const int* in_sizes, int n_in,
                              void* d_out, int out_size, void* d_ws, size_t ws_size,
                              hipStream_t stream){
  const float* x    = (const float*)d_in[0];
  const int*   ei   = (const int*)d_in[1];
  const int*   batch= (const int*)d_in[2];
  const float* Wp   = (const float*)d_in[3];
  const float* bp   = (const float*)d_in[4];
  const float* Wg   = (const float*)d_in[5];
  const float* asrc = (const float*)d_in[6];
  const float* adst = (const float*)d_in[7];
  const float* bg   = (const float*)d_in[8];
  const float* gamma= (const float*)d_in[9];
  const float* beta = (const float*)d_in[10];
  const float* hW1  = (const float*)d_in[11];
  const float* hb1  = (const float*)d_in[12];
  const float* hW2  = (const float*)d_in[13];
  const float* hb2  = (const float*)d_in[14];
  float* out = (float*)d_out;

  const int E = in_sizes[1] / 2;
  const int N = in_sizes[2];
  const int G = out_size / 3;
  const int WTOT = in_sizes[5];           // L*D*D
  const int L = WTOT / 16384;

  char* w = (char*)d_ws;
  auto alloc = [&](size_t bytes){ char* p = w; w += (bytes + 255) & ~(size_t)255; return p; };
  ushort* h     = (ushort*)alloc((size_t)N*D*2);
  ushort* xh    = (ushort*)alloc((size_t)N*D*2);
  float* sc2    = (float*)alloc((size_t)N*16*4);
  // zero-initialized region: deg + bnsumL only (col needs no pre-zero now)
  int*   deg    = (int*)  alloc((size_t)N*4);
  float* bnsumL = (float*)alloc((size_t)4*NSLICE*256*4);   // per-layer slices
  char*  zend   = w;
  int*   col    = (int*)  alloc(((size_t)N*MAXDEG + 64)*4);
  int*   gs     = (int*)  alloc((size_t)(G + 1)*4);
  ushort* WtB   = (ushort*)alloc((size_t)L*WROWS*D*2);

  hipMemsetAsync(deg, 0, (size_t)(zend - (char*)deg), stream);

  const int bInit = (N*32 + 255)/256;
  const int bGb   = (N + 255)/256;
  const int bWp   = (WTOT + 255)/256;
  const int bWsc  = (WTOT/8 + 255)/256;   // L*16*128 elements
  const int bSc   = (E + 255)/256;
  k_setup<<<bInit + bGb + bWp + bWsc + bSc, 256, 0, stream>>>(
      x, Wp, bp, h, batch, gs, Wg, asrc, adst, WtB,
      ei, deg, col, N, G, WTOT, E, bInit, bGb, bWp, bWsc);

  for (int l = 0; l < 4; l++){
    float* bnPrev = bnsumL + (size_t)(l - 1)*NSLICE*256;   // unused when l==0
    float* bnCur  = bnsumL + (size_t)l*NSLICE*256;
    k_gemm<<<(N + 255)/256, 512, 0, stream>>>(h, WtB + (size_t)l*WROWS*D, xh, sc2,
                                              l == 0 ? bnCur : bnPrev,
                                              gamma + l*D, beta + l*D, N, l == 0);
    k_agg<<<(N + 15)/16, 512, 0, stream>>>((const uint*)xh, sc2, deg, col,
                                           bg + l*D, h, bnCur, N);
  }

  k_poolheads<<<G, 128, 0, stream>>>(h, gs, bnsumL + (size_t)3*NSLICE*256,
                                     gamma + 3*D, beta + 3*D,
                                     hW1, hb1, hW2, hb2, out, N);
}